// Round 6
// baseline (1238.259 us; speedup 1.0000x reference)
//
#include <hip/hip_runtime.h>
#include <hip/hip_bf16.h>
#include <cstddef>

// ---------------------------------------------------------------------------
// 3-layer GAT (PyG-style) on MI355X.
// Round 5 (resubmit): GEMM KB=32 + register double-buffered staging; attention
// logits (al_s/al_d) fused into the GEMM epilogue (block owns 2 whole heads).
// h stored fp16 (gather at the 8-XCD private-L2 re-fetch floor, ~213MB).
// ---------------------------------------------------------------------------

typedef _Float16 h4 __attribute__((ext_vector_type(4)));

#define ECAP 96  // LDS-cached logits per node; deg>ECAP falls back to re-gather

// ---------------- CSR build ----------------

__global__ void zero_i32(int* __restrict__ p, int n) {
  int i = blockIdx.x * 256 + threadIdx.x;
  if (i < n) p[i] = 0;
}

__global__ void edge_histogram(const int* __restrict__ ei, int E, int nnodes,
                               int* __restrict__ counts) {
  int e = blockIdx.x * 256 + threadIdx.x;
  int tot = E + nnodes;
  if (e >= tot) return;
  int dst = (e < E) ? ei[E + e] : (e - E);
  atomicAdd(&counts[dst], 1);
}

__global__ void scan_block(const int* __restrict__ in, int* __restrict__ out,
                           int* __restrict__ sums, int n) {
  __shared__ int tmp[256];
  int i = blockIdx.x * 256 + threadIdx.x;
  int v = (i < n) ? in[i] : 0;
  tmp[threadIdx.x] = v;
  __syncthreads();
  for (int off = 1; off < 256; off <<= 1) {
    int t = (threadIdx.x >= off) ? tmp[threadIdx.x - off] : 0;
    __syncthreads();
    tmp[threadIdx.x] += t;
    __syncthreads();
  }
  if (i < n) out[i] = tmp[threadIdx.x] - v;  // exclusive
  if (sums && threadIdx.x == 255) sums[blockIdx.x] = tmp[255];
}

__global__ void add_offsets(int* __restrict__ row_ptr, const int* __restrict__ offs,
                            int* __restrict__ nextp, int n, int total) {
  int i = blockIdx.x * 256 + threadIdx.x;
  if (i < n) {
    int v = row_ptr[i] + offs[blockIdx.x];
    row_ptr[i] = v;
    nextp[i] = v;
  }
  if (i == 0) row_ptr[n] = total;
}

__global__ void edge_scatter(const int* __restrict__ ei, int E, int nnodes,
                             int* __restrict__ nextp, int* __restrict__ col_idx) {
  int e = blockIdx.x * 256 + threadIdx.x;
  int tot = E + nnodes;
  if (e >= tot) return;
  int src = (e < E) ? ei[e] : (e - E);
  int dst = (e < E) ? ei[E + e] : (e - E);
  int pos = atomicAdd(&nextp[dst], 1);
  col_idx[pos] = src;
}

// ---------------- fused GEMM + al: h16 = A@B (fp32 math), al_s/al_d --------
// N fixed at 256, BM=128, BN=128, KB=32, 256 threads, 8x8 per thread.
// Register double-buffer: next tile's global loads issued before the FMA
// burst. Block (bx,by) owns heads {2by, 2by+1} entirely -> al via 16-lane
// shuffle reduce, no atomics.

#define LOAD_TILE(k0)                                                        \
  do {                                                                       \
    _Pragma("unroll") for (int r = 0; r < 4; ++r) {                          \
      int f = t + r * 256;                                                   \
      int row = f >> 3, kq = f & 7;                                          \
      int gr = m0 + row;                                                     \
      ra[r] = (gr < M) ? *(const float4*)&A[(size_t)gr * K + (k0) + kq * 4]  \
                       : make_float4(0.f, 0.f, 0.f, 0.f);                    \
      int kr = f >> 5, cq = f & 31;                                          \
      rb[r] = *(const float4*)&B[(size_t)((k0) + kr) * 256 + n0 + cq * 4];   \
    }                                                                        \
  } while (0)

#define WRITE_TILE()                                                         \
  do {                                                                       \
    _Pragma("unroll") for (int r = 0; r < 4; ++r) {                          \
      int f = t + r * 256;                                                   \
      int row = f >> 3, kq = f & 7;                                          \
      As[kq * 4 + 0][row] = ra[r].x;                                         \
      As[kq * 4 + 1][row] = ra[r].y;                                         \
      As[kq * 4 + 2][row] = ra[r].z;                                         \
      As[kq * 4 + 3][row] = ra[r].w;                                         \
      int kr = f >> 5, cq = f & 31;                                          \
      *(float4*)&Bs[kr][cq * 4] = rb[r];                                     \
    }                                                                        \
  } while (0)

__global__ __launch_bounds__(256) void gemm_al(
    const float* __restrict__ A, const float* __restrict__ B,
    _Float16* __restrict__ C16, const float* __restrict__ a_src,
    const float* __restrict__ a_dst, float* __restrict__ alS,
    float* __restrict__ alD, int M, int K) {
  __shared__ float As[32][128 + 4];
  __shared__ float Bs[32][128];
  int t = threadIdx.x;
  int m0 = blockIdx.x * 128;
  int by = blockIdx.y;
  int n0 = by * 128;
  int tx = t & 15, ty = t >> 4;

  float4 ra[4], rb[4];
  float c[2][2][4][4];
#pragma unroll
  for (int a = 0; a < 2; ++a)
#pragma unroll
    for (int b = 0; b < 2; ++b)
#pragma unroll
      for (int i = 0; i < 4; ++i)
#pragma unroll
        for (int j = 0; j < 4; ++j) c[a][b][i][j] = 0.f;

  int ntiles = K >> 5;
  LOAD_TILE(0);
  WRITE_TILE();
  for (int tt = 0; tt < ntiles; ++tt) {
    __syncthreads();  // LDS tile ready
    if (tt + 1 < ntiles) LOAD_TILE((tt + 1) * 32);
#pragma unroll
    for (int k = 0; k < 32; ++k) {
      float4 a0 = *(const float4*)&As[k][ty * 4];
      float4 a1 = *(const float4*)&As[k][64 + ty * 4];
      float4 b0 = *(const float4*)&Bs[k][tx * 4];
      float4 b1 = *(const float4*)&Bs[k][64 + tx * 4];
      float av[2][4] = {{a0.x, a0.y, a0.z, a0.w}, {a1.x, a1.y, a1.z, a1.w}};
      float bv[2][4] = {{b0.x, b0.y, b0.z, b0.w}, {b1.x, b1.y, b1.z, b1.w}};
#pragma unroll
      for (int ih = 0; ih < 2; ++ih)
#pragma unroll
        for (int jh = 0; jh < 2; ++jh)
#pragma unroll
          for (int i = 0; i < 4; ++i)
#pragma unroll
            for (int j = 0; j < 4; ++j)
              c[ih][jh][i][j] += av[ih][i] * bv[jh][j];
    }
    __syncthreads();  // all reads done before overwrite
    if (tt + 1 < ntiles) WRITE_TILE();
  }

  // ---- epilogue: h16 store + fused al (heads 2by, 2by+1) ----
  float4 asv0 = *(const float4*)&a_src[(by * 2 + 0) * 64 + tx * 4];
  float4 asv1 = *(const float4*)&a_src[(by * 2 + 1) * 64 + tx * 4];
  float4 adv0 = *(const float4*)&a_dst[(by * 2 + 0) * 64 + tx * 4];
  float4 adv1 = *(const float4*)&a_dst[(by * 2 + 1) * 64 + tx * 4];
#pragma unroll
  for (int ih = 0; ih < 2; ++ih)
#pragma unroll
    for (int i = 0; i < 4; ++i) {
      int gr = m0 + ih * 64 + ty * 4 + i;
      float* c0 = c[ih][0][i];
      float* c1 = c[ih][1][i];
      float ps0 = c0[0] * asv0.x + c0[1] * asv0.y + c0[2] * asv0.z + c0[3] * asv0.w;
      float pd0 = c0[0] * adv0.x + c0[1] * adv0.y + c0[2] * adv0.z + c0[3] * adv0.w;
      float ps1 = c1[0] * asv1.x + c1[1] * asv1.y + c1[2] * asv1.z + c1[3] * asv1.w;
      float pd1 = c1[0] * adv1.x + c1[1] * adv1.y + c1[2] * adv1.z + c1[3] * adv1.w;
#pragma unroll
      for (int off = 1; off < 16; off <<= 1) {
        ps0 += __shfl_xor(ps0, off);
        pd0 += __shfl_xor(pd0, off);
        ps1 += __shfl_xor(ps1, off);
        pd1 += __shfl_xor(pd1, off);
      }
      if (gr < M) {
        h4 v0 = {(_Float16)c0[0], (_Float16)c0[1], (_Float16)c0[2],
                 (_Float16)c0[3]};
        h4 v1 = {(_Float16)c1[0], (_Float16)c1[1], (_Float16)c1[2],
                 (_Float16)c1[3]};
        *(h4*)&C16[(size_t)gr * 256 + n0 + tx * 4] = v0;
        *(h4*)&C16[(size_t)gr * 256 + n0 + 64 + tx * 4] = v1;
        if (tx == 0) {
          alS[gr * 4 + by * 2 + 0] = ps0;
          alS[gr * 4 + by * 2 + 1] = ps1;
          alD[gr * 4 + by * 2 + 0] = pd0;
          alD[gr * 4 + by * 2 + 1] = pd1;
        }
      }
    }
}

// ---------------- per-dst two-pass softmax aggregation (heads=4, C=64) ------

template <bool RELU>
__global__ __launch_bounds__(256) void gat_aggregate(
    const _Float16* __restrict__ h, const float* __restrict__ al_s,
    const float* __restrict__ al_d, const int* __restrict__ row_ptr,
    const int* __restrict__ col_idx, const float* __restrict__ bias,
    float* __restrict__ out, int nnodes) {
  __shared__ float e_lds[4][ECAP * 4];
  int wv = threadIdx.x >> 6;
  int n = blockIdx.x * 4 + wv;
  if (n >= nnodes) return;
  int l = threadIdx.x & 63;
  int hd = l >> 4;
  int sub = l & 15;
  int beg = row_ptr[n], end = row_ptr[n + 1];
  int deg = end - beg;
  float ad = al_d[n * 4 + hd];

  // ---- pass 1: logits + max ----
  float m = -3.0e38f;
  for (int j0 = 0; j0 < deg; j0 += 16) {
    int j = j0 + sub;
    float e = -3.0e38f;
    if (j < deg) {
      int src = col_idx[beg + j];
      e = al_s[src * 4 + hd] + ad;
      e = fmaxf(e, 0.2f * e);  // leaky_relu(0.2)
      if (j < ECAP) e_lds[wv][j * 4 + hd] = e;
    }
    m = fmaxf(m, e);
  }
#pragma unroll
  for (int off = 1; off < 16; off <<= 1) m = fmaxf(m, __shfl_xor(m, off));
  __syncthreads();

  // ---- pass 2: p = exp(e - m), fp16 gather-FMA, unrolled x8 ----
  float s = 0.f;
  float4 acc = {0.f, 0.f, 0.f, 0.f};
  int jcap = deg < ECAP ? deg : ECAP;
  int j = 0;
  for (; j + 8 <= jcap; j += 8) {
    int si[8];
    h4 hv[8];
    float p[8];
#pragma unroll
    for (int u = 0; u < 8; ++u) si[u] = col_idx[beg + j + u];
#pragma unroll
    for (int u = 0; u < 8; ++u)
      hv[u] = *(const h4*)&h[(size_t)si[u] * 256 + l * 4];
#pragma unroll
    for (int u = 0; u < 8; ++u) p[u] = __expf(e_lds[wv][(j + u) * 4 + hd] - m);
#pragma unroll
    for (int u = 0; u < 8; ++u) {
      s += p[u];
      acc.x += p[u] * (float)hv[u][0];
      acc.y += p[u] * (float)hv[u][1];
      acc.z += p[u] * (float)hv[u][2];
      acc.w += p[u] * (float)hv[u][3];
    }
  }
  for (; j < deg; ++j) {
    int src = col_idx[beg + j];
    float e;
    if (j < ECAP) {
      e = e_lds[wv][j * 4 + hd];
    } else {  // fallback for pathological degree
      e = al_s[src * 4 + hd] + ad;
      e = fmaxf(e, 0.2f * e);
    }
    float p = __expf(e - m);
    s += p;
    h4 hv = *(const h4*)&h[(size_t)src * 256 + l * 4];
    acc.x += p * (float)hv[0];
    acc.y += p * (float)hv[1];
    acc.z += p * (float)hv[2];
    acc.w += p * (float)hv[3];
  }
  float inv = 1.f / (s + 1e-16f);
  float4 bv = *(const float4*)&bias[l * 4];
  float4 o = {acc.x * inv + bv.x, acc.y * inv + bv.y, acc.z * inv + bv.z,
              acc.w * inv + bv.w};
  if (RELU) {
    o.x = fmaxf(o.x, 0.f);
    o.y = fmaxf(o.y, 0.f);
    o.z = fmaxf(o.z, 0.f);
    o.w = fmaxf(o.w, 0.f);
  }
  *(float4*)&out[(size_t)n * 256 + l * 4] = o;
}

// ---------------- layer 3: tiny GEMM (256->5) fused with al3 ----------------

__global__ __launch_bounds__(256) void gemm3_al(const float* __restrict__ Hin,
                                                const float* __restrict__ W3,
                                                const float* __restrict__ a_src3,
                                                const float* __restrict__ a_dst3,
                                                float* __restrict__ h3,
                                                float* __restrict__ al_s,
                                                float* __restrict__ al_d,
                                                int nnodes) {
  int n = blockIdx.x * 4 + (threadIdx.x >> 6);
  if (n >= nnodes) return;
  int l = threadIdx.x & 63;
  float4 hv = *(const float4*)&Hin[(size_t)n * 256 + l * 4];
  float acc[5];
#pragma unroll
  for (int cc = 0; cc < 5; ++cc) {
    acc[cc] = hv.x * W3[(l * 4 + 0) * 5 + cc] + hv.y * W3[(l * 4 + 1) * 5 + cc] +
              hv.z * W3[(l * 4 + 2) * 5 + cc] + hv.w * W3[(l * 4 + 3) * 5 + cc];
  }
#pragma unroll
  for (int cc = 0; cc < 5; ++cc)
#pragma unroll
    for (int off = 32; off; off >>= 1) acc[cc] += __shfl_xor(acc[cc], off);
  if (l == 0) {
    float as = 0.f, adv = 0.f;
#pragma unroll
    for (int cc = 0; cc < 5; ++cc) {
      h3[(size_t)n * 5 + cc] = acc[cc];
      as += acc[cc] * a_src3[cc];
      adv += acc[cc] * a_dst3[cc];
    }
    al_s[n] = as;
    al_d[n] = adv;
  }
}

// two-pass (parallel logits, no serial exp-rescale chain), heads=1, C=5

__global__ __launch_bounds__(256) void gat_aggregate3(
    const float* __restrict__ h3, const float* __restrict__ al_s,
    const float* __restrict__ al_d, const int* __restrict__ row_ptr,
    const int* __restrict__ col_idx, const float* __restrict__ b3,
    float* __restrict__ out, int nnodes) {
  __shared__ float e_lds[4][ECAP];
  int wv = threadIdx.x >> 6;
  int n = blockIdx.x * 4 + wv;
  if (n >= nnodes) return;
  int l = threadIdx.x & 63;
  int beg = row_ptr[n], end = row_ptr[n + 1];
  int deg = end - beg;
  float ad = al_d[n];

  // pass 1: all 64 lanes compute logits in parallel
  float m = -3.0e38f;
  for (int j0 = 0; j0 < deg; j0 += 64) {
    int j = j0 + l;
    float e = -3.0e38f;
    if (j < deg) {
      int src = col_idx[beg + j];
      e = al_s[src] + ad;
      e = fmaxf(e, 0.2f * e);
      if (j < ECAP) e_lds[wv][j] = e;
    }
    m = fmaxf(m, e);
  }
#pragma unroll
  for (int off = 1; off < 64; off <<= 1) m = fmaxf(m, __shfl_xor(m, off));

  // s: parallel partial sums over LDS/recomputed logits
  float sp = 0.f;
  for (int j = l; j < deg; j += 64) {
    float e;
    if (j < ECAP) {
      e = e_lds[wv][j];
    } else {
      int src = col_idx[beg + j];
      e = al_s[src] + ad;
      e = fmaxf(e, 0.2f * e);
    }
    sp += __expf(e - m);
  }
#pragma unroll
  for (int off = 1; off < 64; off <<= 1) sp += __shfl_xor(sp, off);
  float s = sp;

  // pass 2: lanes 0..4 gather h3 and accumulate (h3 is 1MB, L2-resident)
  float acc = 0.f;
  if (l < 5) {
    for (int j = 0; j < deg; ++j) {
      float e;
      if (j < ECAP) {
        e = e_lds[wv][j];
      } else {
        int src0 = col_idx[beg + j];
        e = al_s[src0] + ad;
        e = fmaxf(e, 0.2f * e);
      }
      float p = __expf(e - m);
      int src = col_idx[beg + j];
      acc += p * h3[(size_t)src * 5 + l];
    }
    out[(size_t)n * 5 + l] = acc / (s + 1e-16f) + b3[l];
  }
}

// ---------------- launch ----------------

extern "C" void kernel_launch(void* const* d_in, const int* in_sizes, int n_in,
                              void* d_out, int out_size, void* d_ws, size_t ws_size,
                              hipStream_t stream) {
  const float* x = (const float*)d_in[0];
  const int* ei = (const int*)d_in[1];
  const float* W1 = (const float*)d_in[2];
  const float* as1 = (const float*)d_in[3];
  const float* ad1 = (const float*)d_in[4];
  const float* b1 = (const float*)d_in[5];
  const float* W2 = (const float*)d_in[6];
  const float* as2 = (const float*)d_in[7];
  const float* ad2 = (const float*)d_in[8];
  const float* b2 = (const float*)d_in[9];
  const float* W3 = (const float*)d_in[10];
  const float* as3 = (const float*)d_in[11];
  const float* ad3 = (const float*)d_in[12];
  const float* b3 = (const float*)d_in[13];

  int N = in_sizes[0] / 128;  // 50000
  int E = in_sizes[1] / 2;    // 800000
  int tot = E + N;            // 850000

  char* w = (char*)d_ws;
  size_t off = 0;
  auto alloc = [&](size_t bytes) -> void* {
    void* p = w + off;
    off += (bytes + 255) & ~(size_t)255;
    return p;
  };
  _Float16* h16 = (_Float16*)alloc((size_t)N * 256 * 2);
  float* bufB = (float*)alloc((size_t)N * 256 * 4);
  float* bufC = (float*)alloc((size_t)N * 256 * 4);
  float* h3 = (float*)alloc((size_t)N * 5 * 4);
  float* alS = (float*)alloc((size_t)N * 4 * 4);
  float* alD = (float*)alloc((size_t)N * 4 * 4);
  int* row_ptr = (int*)alloc(((size_t)N + 1) * 4);
  int* nextp = (int*)alloc((size_t)N * 4);
  int* bsums = (int*)alloc(256 * 4);
  int* col_idx = (int*)alloc((size_t)tot * 4);
  (void)ws_size;

  int nbN = (N + 255) / 256;
  int nbE = (tot + 255) / 256;
  int nb4 = (N + 3) / 4;

  // CSR build (counts live in nextp)
  zero_i32<<<nbN, 256, 0, stream>>>(nextp, N);
  edge_histogram<<<nbE, 256, 0, stream>>>(ei, E, N, nextp);
  scan_block<<<nbN, 256, 0, stream>>>(nextp, row_ptr, bsums, N);
  scan_block<<<1, 256, 0, stream>>>(bsums, bsums, nullptr, nbN);
  add_offsets<<<nbN, 256, 0, stream>>>(row_ptr, bsums, nextp, N, tot);
  edge_scatter<<<nbE, 256, 0, stream>>>(ei, E, N, nextp, col_idx);

  dim3 g1((N + 127) / 128, 2);

  // layer 1
  gemm_al<<<g1, 256, 0, stream>>>(x, W1, h16, as1, ad1, alS, alD, N, 128);
  gat_aggregate<true><<<nb4, 256, 0, stream>>>(h16, alS, alD, row_ptr, col_idx,
                                               b1, bufB, N);
  // layer 2
  gemm_al<<<g1, 256, 0, stream>>>(bufB, W2, h16, as2, ad2, alS, alD, N, 256);
  gat_aggregate<true><<<nb4, 256, 0, stream>>>(h16, alS, alD, row_ptr, col_idx,
                                               b2, bufC, N);
  // layer 3
  gemm3_al<<<nb4, 256, 0, stream>>>(bufC, W3, as3, ad3, h3, alS, alD, N);
  gat_aggregate3<<<nb4, 256, 0, stream>>>(h3, alS, alD, row_ptr, col_idx, b3,
                                          (float*)d_out, N);
}

// Round 7
// 572.103 us; speedup vs baseline: 2.1644x; 2.1644x over previous
//
#include <hip/hip_runtime.h>
#include <hip/hip_bf16.h>
#include <cstddef>

// ---------------------------------------------------------------------------
// 3-layer GAT (PyG-style) on MI355X.
// Round 7: round-4 GEMM structure (KB=16, LDS staging, VGPR=72) + fused al
// epilogue with DIRECT constant indexing (round-5's pointer-into-local-array
// epilogue forced the accumulator to scratch: VGPR=256, 1.7GB HBM, 5.5x slow).
// h stored fp16 (gather at the 8-XCD private-L2 re-fetch floor, ~213MB).
// ---------------------------------------------------------------------------

typedef _Float16 h4 __attribute__((ext_vector_type(4)));

#define ECAP 96  // LDS-cached logits per node; deg>ECAP falls back to re-gather

// ---------------- CSR build ----------------

__global__ void zero_i32(int* __restrict__ p, int n) {
  int i = blockIdx.x * 256 + threadIdx.x;
  if (i < n) p[i] = 0;
}

__global__ void edge_histogram(const int* __restrict__ ei, int E, int nnodes,
                               int* __restrict__ counts) {
  int e = blockIdx.x * 256 + threadIdx.x;
  int tot = E + nnodes;
  if (e >= tot) return;
  int dst = (e < E) ? ei[E + e] : (e - E);
  atomicAdd(&counts[dst], 1);
}

__global__ void scan_block(const int* __restrict__ in, int* __restrict__ out,
                           int* __restrict__ sums, int n) {
  __shared__ int tmp[256];
  int i = blockIdx.x * 256 + threadIdx.x;
  int v = (i < n) ? in[i] : 0;
  tmp[threadIdx.x] = v;
  __syncthreads();
  for (int off = 1; off < 256; off <<= 1) {
    int t = (threadIdx.x >= off) ? tmp[threadIdx.x - off] : 0;
    __syncthreads();
    tmp[threadIdx.x] += t;
    __syncthreads();
  }
  if (i < n) out[i] = tmp[threadIdx.x] - v;  // exclusive
  if (sums && threadIdx.x == 255) sums[blockIdx.x] = tmp[255];
}

__global__ void add_offsets(int* __restrict__ row_ptr, const int* __restrict__ offs,
                            int* __restrict__ nextp, int n, int total) {
  int i = blockIdx.x * 256 + threadIdx.x;
  if (i < n) {
    int v = row_ptr[i] + offs[blockIdx.x];
    row_ptr[i] = v;
    nextp[i] = v;
  }
  if (i == 0) row_ptr[n] = total;
}

__global__ void edge_scatter(const int* __restrict__ ei, int E, int nnodes,
                             int* __restrict__ nextp, int* __restrict__ col_idx) {
  int e = blockIdx.x * 256 + threadIdx.x;
  int tot = E + nnodes;
  if (e >= tot) return;
  int src = (e < E) ? ei[e] : (e - E);
  int dst = (e < E) ? ei[E + e] : (e - E);
  int pos = atomicAdd(&nextp[dst], 1);
  col_idx[pos] = src;
}

// ---------------- fused GEMM + al: h16 = A@B (fp32 math), al_s/al_d --------
// N fixed at 256, BM=128, BN=128, KB=16, 256 threads, 8x8 per thread.
// Block (bx,by) owns heads {2by, 2by+1} entirely -> al via 16-lane shuffle
// reduce in the epilogue, computed from fp32 accumulators (pre-rounding).

__global__ __launch_bounds__(256) void gemm_al(
    const float* __restrict__ A, const float* __restrict__ B,
    _Float16* __restrict__ C16, const float* __restrict__ a_src,
    const float* __restrict__ a_dst, float* __restrict__ alS,
    float* __restrict__ alD, int M, int K) {
  __shared__ float As[16][128 + 4];
  __shared__ float Bs[16][128];
  int t = threadIdx.x;
  int m0 = blockIdx.x * 128;
  int by = blockIdx.y;
  int n0 = by * 128;
  int tx = t & 15, ty = t >> 4;

  float c[2][2][4][4];
#pragma unroll
  for (int a = 0; a < 2; ++a)
#pragma unroll
    for (int b = 0; b < 2; ++b)
#pragma unroll
      for (int i = 0; i < 4; ++i)
#pragma unroll
        for (int j = 0; j < 4; ++j) c[a][b][i][j] = 0.f;

  for (int k0 = 0; k0 < K; k0 += 16) {
    // A tile: 128 rows x 16 k, transposed into As[k][m]
#pragma unroll
    for (int r = 0; r < 2; ++r) {
      int idx = t + r * 256;
      int row = idx >> 2;
      int quad = idx & 3;
      float4 v = {0.f, 0.f, 0.f, 0.f};
      int gr = m0 + row;
      if (gr < M) v = *(const float4*)&A[(size_t)gr * K + k0 + quad * 4];
      As[quad * 4 + 0][row] = v.x;
      As[quad * 4 + 1][row] = v.y;
      As[quad * 4 + 2][row] = v.z;
      As[quad * 4 + 3][row] = v.w;
    }
    // B tile: 16 k-rows x 128 cols
#pragma unroll
    for (int r = 0; r < 2; ++r) {
      int idx = t + r * 256;
      int krow = idx >> 5;
      int q = idx & 31;
      float4 v = *(const float4*)&B[(size_t)(k0 + krow) * 256 + n0 + q * 4];
      *(float4*)&Bs[krow][q * 4] = v;
    }
    __syncthreads();
#pragma unroll
    for (int k = 0; k < 16; ++k) {
      float4 a0 = *(const float4*)&As[k][ty * 4];
      float4 a1 = *(const float4*)&As[k][64 + ty * 4];
      float4 b0 = *(const float4*)&Bs[k][tx * 4];
      float4 b1 = *(const float4*)&Bs[k][64 + tx * 4];
      float av[2][4] = {{a0.x, a0.y, a0.z, a0.w}, {a1.x, a1.y, a1.z, a1.w}};
      float bv[2][4] = {{b0.x, b0.y, b0.z, b0.w}, {b1.x, b1.y, b1.z, b1.w}};
#pragma unroll
      for (int ih = 0; ih < 2; ++ih)
#pragma unroll
        for (int jh = 0; jh < 2; ++jh)
#pragma unroll
          for (int i = 0; i < 4; ++i)
#pragma unroll
            for (int j = 0; j < 4; ++j)
              c[ih][jh][i][j] += av[ih][i] * bv[jh][j];
    }
    __syncthreads();
  }

  // ---- epilogue: h16 store + fused al (heads 2by, 2by+1), no pointers ----
  float4 asv0 = *(const float4*)&a_src[(by * 2 + 0) * 64 + tx * 4];
  float4 asv1 = *(const float4*)&a_src[(by * 2 + 1) * 64 + tx * 4];
  float4 adv0 = *(const float4*)&a_dst[(by * 2 + 0) * 64 + tx * 4];
  float4 adv1 = *(const float4*)&a_dst[(by * 2 + 1) * 64 + tx * 4];
#pragma unroll
  for (int ih = 0; ih < 2; ++ih)
#pragma unroll
    for (int i = 0; i < 4; ++i) {
      int gr = m0 + ih * 64 + ty * 4 + i;
      float ps0 = c[ih][0][i][0] * asv0.x + c[ih][0][i][1] * asv0.y +
                  c[ih][0][i][2] * asv0.z + c[ih][0][i][3] * asv0.w;
      float pd0 = c[ih][0][i][0] * adv0.x + c[ih][0][i][1] * adv0.y +
                  c[ih][0][i][2] * adv0.z + c[ih][0][i][3] * adv0.w;
      float ps1 = c[ih][1][i][0] * asv1.x + c[ih][1][i][1] * asv1.y +
                  c[ih][1][i][2] * asv1.z + c[ih][1][i][3] * asv1.w;
      float pd1 = c[ih][1][i][0] * adv1.x + c[ih][1][i][1] * adv1.y +
                  c[ih][1][i][2] * adv1.z + c[ih][1][i][3] * adv1.w;
#pragma unroll
      for (int off = 1; off < 16; off <<= 1) {
        ps0 += __shfl_xor(ps0, off);
        pd0 += __shfl_xor(pd0, off);
        ps1 += __shfl_xor(ps1, off);
        pd1 += __shfl_xor(pd1, off);
      }
      if (gr < M) {
        h4 v0 = {(_Float16)c[ih][0][i][0], (_Float16)c[ih][0][i][1],
                 (_Float16)c[ih][0][i][2], (_Float16)c[ih][0][i][3]};
        h4 v1 = {(_Float16)c[ih][1][i][0], (_Float16)c[ih][1][i][1],
                 (_Float16)c[ih][1][i][2], (_Float16)c[ih][1][i][3]};
        *(h4*)&C16[(size_t)gr * 256 + n0 + tx * 4] = v0;
        *(h4*)&C16[(size_t)gr * 256 + n0 + 64 + tx * 4] = v1;
        if (tx == 0) {
          alS[gr * 4 + by * 2 + 0] = ps0;
          alS[gr * 4 + by * 2 + 1] = ps1;
          alD[gr * 4 + by * 2 + 0] = pd0;
          alD[gr * 4 + by * 2 + 1] = pd1;
        }
      }
    }
}

// ---------------- per-dst two-pass softmax aggregation (heads=4, C=64) ------

template <bool RELU>
__global__ __launch_bounds__(256) void gat_aggregate(
    const _Float16* __restrict__ h, const float* __restrict__ al_s,
    const float* __restrict__ al_d, const int* __restrict__ row_ptr,
    const int* __restrict__ col_idx, const float* __restrict__ bias,
    float* __restrict__ out, int nnodes) {
  __shared__ float e_lds[4][ECAP * 4];
  int wv = threadIdx.x >> 6;
  int n = blockIdx.x * 4 + wv;
  if (n >= nnodes) return;
  int l = threadIdx.x & 63;
  int hd = l >> 4;
  int sub = l & 15;
  int beg = row_ptr[n], end = row_ptr[n + 1];
  int deg = end - beg;
  float ad = al_d[n * 4 + hd];

  // ---- pass 1: logits + max ----
  float m = -3.0e38f;
  for (int j0 = 0; j0 < deg; j0 += 16) {
    int j = j0 + sub;
    float e = -3.0e38f;
    if (j < deg) {
      int src = col_idx[beg + j];
      e = al_s[src * 4 + hd] + ad;
      e = fmaxf(e, 0.2f * e);  // leaky_relu(0.2)
      if (j < ECAP) e_lds[wv][j * 4 + hd] = e;
    }
    m = fmaxf(m, e);
  }
#pragma unroll
  for (int off = 1; off < 16; off <<= 1) m = fmaxf(m, __shfl_xor(m, off));
  __syncthreads();

  // ---- pass 2: p = exp(e - m), fp16 gather-FMA, unrolled x8 ----
  float s = 0.f;
  float4 acc = {0.f, 0.f, 0.f, 0.f};
  int jcap = deg < ECAP ? deg : ECAP;
  int j = 0;
  for (; j + 8 <= jcap; j += 8) {
    int si[8];
    h4 hv[8];
    float p[8];
#pragma unroll
    for (int u = 0; u < 8; ++u) si[u] = col_idx[beg + j + u];
#pragma unroll
    for (int u = 0; u < 8; ++u)
      hv[u] = *(const h4*)&h[(size_t)si[u] * 256 + l * 4];
#pragma unroll
    for (int u = 0; u < 8; ++u) p[u] = __expf(e_lds[wv][(j + u) * 4 + hd] - m);
#pragma unroll
    for (int u = 0; u < 8; ++u) {
      s += p[u];
      acc.x += p[u] * (float)hv[u][0];
      acc.y += p[u] * (float)hv[u][1];
      acc.z += p[u] * (float)hv[u][2];
      acc.w += p[u] * (float)hv[u][3];
    }
  }
  for (; j < deg; ++j) {
    int src = col_idx[beg + j];
    float e;
    if (j < ECAP) {
      e = e_lds[wv][j * 4 + hd];
    } else {  // fallback for pathological degree
      e = al_s[src * 4 + hd] + ad;
      e = fmaxf(e, 0.2f * e);
    }
    float p = __expf(e - m);
    s += p;
    h4 hv = *(const h4*)&h[(size_t)src * 256 + l * 4];
    acc.x += p * (float)hv[0];
    acc.y += p * (float)hv[1];
    acc.z += p * (float)hv[2];
    acc.w += p * (float)hv[3];
  }
  float inv = 1.f / (s + 1e-16f);
  float4 bv = *(const float4*)&bias[l * 4];
  float4 o = {acc.x * inv + bv.x, acc.y * inv + bv.y, acc.z * inv + bv.z,
              acc.w * inv + bv.w};
  if (RELU) {
    o.x = fmaxf(o.x, 0.f);
    o.y = fmaxf(o.y, 0.f);
    o.z = fmaxf(o.z, 0.f);
    o.w = fmaxf(o.w, 0.f);
  }
  *(float4*)&out[(size_t)n * 256 + l * 4] = o;
}

// ---------------- layer 3: tiny GEMM (256->5) fused with al3 ----------------

__global__ __launch_bounds__(256) void gemm3_al(const float* __restrict__ Hin,
                                                const float* __restrict__ W3,
                                                const float* __restrict__ a_src3,
                                                const float* __restrict__ a_dst3,
                                                float* __restrict__ h3,
                                                float* __restrict__ al_s,
                                                float* __restrict__ al_d,
                                                int nnodes) {
  int n = blockIdx.x * 4 + (threadIdx.x >> 6);
  if (n >= nnodes) return;
  int l = threadIdx.x & 63;
  float4 hv = *(const float4*)&Hin[(size_t)n * 256 + l * 4];
  float acc[5];
#pragma unroll
  for (int cc = 0; cc < 5; ++cc) {
    acc[cc] = hv.x * W3[(l * 4 + 0) * 5 + cc] + hv.y * W3[(l * 4 + 1) * 5 + cc] +
              hv.z * W3[(l * 4 + 2) * 5 + cc] + hv.w * W3[(l * 4 + 3) * 5 + cc];
  }
#pragma unroll
  for (int cc = 0; cc < 5; ++cc)
#pragma unroll
    for (int off = 32; off; off >>= 1) acc[cc] += __shfl_xor(acc[cc], off);
  if (l == 0) {
    float as = 0.f, adv = 0.f;
#pragma unroll
    for (int cc = 0; cc < 5; ++cc) {
      h3[(size_t)n * 5 + cc] = acc[cc];
      as += acc[cc] * a_src3[cc];
      adv += acc[cc] * a_dst3[cc];
    }
    al_s[n] = as;
    al_d[n] = adv;
  }
}

// two-pass (parallel logits, no serial exp-rescale chain), heads=1, C=5

__global__ __launch_bounds__(256) void gat_aggregate3(
    const float* __restrict__ h3, const float* __restrict__ al_s,
    const float* __restrict__ al_d, const int* __restrict__ row_ptr,
    const int* __restrict__ col_idx, const float* __restrict__ b3,
    float* __restrict__ out, int nnodes) {
  __shared__ float e_lds[4][ECAP];
  int wv = threadIdx.x >> 6;
  int n = blockIdx.x * 4 + wv;
  if (n >= nnodes) return;
  int l = threadIdx.x & 63;
  int beg = row_ptr[n], end = row_ptr[n + 1];
  int deg = end - beg;
  float ad = al_d[n];

  // pass 1: all 64 lanes compute logits in parallel
  float m = -3.0e38f;
  for (int j0 = 0; j0 < deg; j0 += 64) {
    int j = j0 + l;
    float e = -3.0e38f;
    if (j < deg) {
      int src = col_idx[beg + j];
      e = al_s[src] + ad;
      e = fmaxf(e, 0.2f * e);
      if (j < ECAP) e_lds[wv][j] = e;
    }
    m = fmaxf(m, e);
  }
#pragma unroll
  for (int off = 1; off < 64; off <<= 1) m = fmaxf(m, __shfl_xor(m, off));

  // s: parallel partial sums over LDS/recomputed logits
  float sp = 0.f;
  for (int j = l; j < deg; j += 64) {
    float e;
    if (j < ECAP) {
      e = e_lds[wv][j];
    } else {
      int src = col_idx[beg + j];
      e = al_s[src] + ad;
      e = fmaxf(e, 0.2f * e);
    }
    sp += __expf(e - m);
  }
#pragma unroll
  for (int off = 1; off < 64; off <<= 1) sp += __shfl_xor(sp, off);
  float s = sp;

  // pass 2: lanes 0..4 gather h3 and accumulate (h3 is 1MB, L2-resident)
  float acc = 0.f;
  if (l < 5) {
    for (int j = 0; j < deg; ++j) {
      float e;
      if (j < ECAP) {
        e = e_lds[wv][j];
      } else {
        int src0 = col_idx[beg + j];
        e = al_s[src0] + ad;
        e = fmaxf(e, 0.2f * e);
      }
      float p = __expf(e - m);
      int src = col_idx[beg + j];
      acc += p * h3[(size_t)src * 5 + l];
    }
    out[(size_t)n * 5 + l] = acc / (s + 1e-16f) + b3[l];
  }
}

// ---------------- launch ----------------

extern "C" void kernel_launch(void* const* d_in, const int* in_sizes, int n_in,
                              void* d_out, int out_size, void* d_ws, size_t ws_size,
                              hipStream_t stream) {
  const float* x = (const float*)d_in[0];
  const int* ei = (const int*)d_in[1];
  const float* W1 = (const float*)d_in[2];
  const float* as1 = (const float*)d_in[3];
  const float* ad1 = (const float*)d_in[4];
  const float* b1 = (const float*)d_in[5];
  const float* W2 = (const float*)d_in[6];
  const float* as2 = (const float*)d_in[7];
  const float* ad2 = (const float*)d_in[8];
  const float* b2 = (const float*)d_in[9];
  const float* W3 = (const float*)d_in[10];
  const float* as3 = (const float*)d_in[11];
  const float* ad3 = (const float*)d_in[12];
  const float* b3 = (const float*)d_in[13];

  int N = in_sizes[0] / 128;  // 50000
  int E = in_sizes[1] / 2;    // 800000
  int tot = E + N;            // 850000

  char* w = (char*)d_ws;
  size_t off = 0;
  auto alloc = [&](size_t bytes) -> void* {
    void* p = w + off;
    off += (bytes + 255) & ~(size_t)255;
    return p;
  };
  _Float16* h16 = (_Float16*)alloc((size_t)N * 256 * 2);
  float* bufB = (float*)alloc((size_t)N * 256 * 4);
  float* bufC = (float*)alloc((size_t)N * 256 * 4);
  float* h3 = (float*)alloc((size_t)N * 5 * 4);
  float* alS = (float*)alloc((size_t)N * 4 * 4);
  float* alD = (float*)alloc((size_t)N * 4 * 4);
  int* row_ptr = (int*)alloc(((size_t)N + 1) * 4);
  int* nextp = (int*)alloc((size_t)N * 4);
  int* bsums = (int*)alloc(256 * 4);
  int* col_idx = (int*)alloc((size_t)tot * 4);
  (void)ws_size;

  int nbN = (N + 255) / 256;
  int nbE = (tot + 255) / 256;
  int nb4 = (N + 3) / 4;

  // CSR build (counts live in nextp)
  zero_i32<<<nbN, 256, 0, stream>>>(nextp, N);
  edge_histogram<<<nbE, 256, 0, stream>>>(ei, E, N, nextp);
  scan_block<<<nbN, 256, 0, stream>>>(nextp, row_ptr, bsums, N);
  scan_block<<<1, 256, 0, stream>>>(bsums, bsums, nullptr, nbN);
  add_offsets<<<nbN, 256, 0, stream>>>(row_ptr, bsums, nextp, N, tot);
  edge_scatter<<<nbE, 256, 0, stream>>>(ei, E, N, nextp, col_idx);

  dim3 g1((N + 127) / 128, 2);

  // layer 1
  gemm_al<<<g1, 256, 0, stream>>>(x, W1, h16, as1, ad1, alS, alD, N, 128);
  gat_aggregate<true><<<nb4, 256, 0, stream>>>(h16, alS, alD, row_ptr, col_idx,
                                               b1, bufB, N);
  // layer 2
  gemm_al<<<g1, 256, 0, stream>>>(bufB, W2, h16, as2, ad2, alS, alD, N, 256);
  gat_aggregate<true><<<nb4, 256, 0, stream>>>(h16, alS, alD, row_ptr, col_idx,
                                               b2, bufC, N);
  // layer 3
  gemm3_al<<<nb4, 256, 0, stream>>>(bufC, W3, as3, ad3, h3, alS, alD, N);
  gat_aggregate3<<<nb4, 256, 0, stream>>>(h3, alS, alD, row_ptr, col_idx, b3,
                                          (float*)d_out, N);
}